// Round 2
// baseline (907.416 us; speedup 1.0000x reference)
//
#include <hip/hip_runtime.h>
#include <hip/hip_bf16.h>

typedef __bf16 bf16_t;
typedef __bf16 bf16x8 __attribute__((ext_vector_type(8)));
typedef __bf16 bf16x4 __attribute__((ext_vector_type(4)));
typedef float f32x4 __attribute__((ext_vector_type(4)));

#define S_LEN 2048
#define HID   2048
#define NH    16
#define HD    128
#define QKVN  2304   // 2048 + 2*128
#define NEG_BIG (-30000.0f)

// ---------------------------------------------------------------------------
// fp32 -> bf16 downcast, float4-vectorized. n must be divisible by 4.
// ---------------------------------------------------------------------------
__global__ __launch_bounds__(256) void cvt_f32_bf16_kernel(
    const float* __restrict__ in, bf16_t* __restrict__ out, int n)
{
  int i = (blockIdx.x * 256 + threadIdx.x) * 4;
  if (i < n) {
    float4 v = *(const float4*)(in + i);
    bf16x4 o;
    o[0] = (bf16_t)v.x; o[1] = (bf16_t)v.y; o[2] = (bf16_t)v.z; o[3] = (bf16_t)v.w;
    *(bf16x4*)(out + i) = o;
  }
}

// ---------------------------------------------------------------------------
// GEMM: C[M,N] (OutT) = A[M,K] (bf16 row-major) @ W[K,N] (bf16 row-major) + bias[N] (f32)
// 128x128 C-tile, BK=32, 256 threads (4 waves), wave handles 32 rows x 128 cols.
// W tile staged transposed in LDS; A fragments straight from global.
// ---------------------------------------------------------------------------
template <typename OutT>
__global__ __launch_bounds__(256) void gemm_bias_kernel(
    const bf16_t* __restrict__ A, const bf16_t* __restrict__ W,
    const float* __restrict__ bias, OutT* __restrict__ C,
    int K, int lda, int ldw, int ldc)
{
  const int WTS = 40;                    // padded stride (elems) of transposed W tile
  __shared__ bf16_t WT[128 * 40];        // WT[n][k], n in [0,128), k in [0,32)

  const int tid  = threadIdx.x;
  const int wave = tid >> 6;
  const int lane = tid & 63;
  const int quad = lane >> 4;
  const int c16  = lane & 15;
  const int n0 = blockIdx.x * 128;
  const int m0 = blockIdx.y * 128;

  f32x4 acc[2][8] = {};

  for (int k0 = 0; k0 < K; k0 += 32) {
    __syncthreads();
    for (int c = tid; c < 512; c += 256) {
      int kk = c >> 4, nc = c & 15;
      bf16x8 v = *(const bf16x8*)(W + (size_t)(k0 + kk) * ldw + n0 + nc * 8);
      #pragma unroll
      for (int j = 0; j < 8; ++j) WT[(nc * 8 + j) * WTS + kk] = v[j];
    }
    __syncthreads();

    bf16x8 af[2];
    #pragma unroll
    for (int rb = 0; rb < 2; ++rb)
      af[rb] = *(const bf16x8*)(A + (size_t)(m0 + wave * 32 + rb * 16 + c16) * lda
                                 + k0 + quad * 8);
    #pragma unroll
    for (int nt = 0; nt < 8; ++nt) {
      bf16x8 bfrag = *(const bf16x8*)(WT + (c16 + nt * 16) * WTS + quad * 8);
      acc[0][nt] = __builtin_amdgcn_mfma_f32_16x16x32_bf16(af[0], bfrag, acc[0][nt], 0, 0, 0);
      acc[1][nt] = __builtin_amdgcn_mfma_f32_16x16x32_bf16(af[1], bfrag, acc[1][nt], 0, 0, 0);
    }
  }

  #pragma unroll
  for (int nt = 0; nt < 8; ++nt) {
    int col = n0 + nt * 16 + c16;
    float bv = bias[col];
    #pragma unroll
    for (int rb = 0; rb < 2; ++rb) {
      int rbase = m0 + wave * 32 + rb * 16 + quad * 4;
      #pragma unroll
      for (int r = 0; r < 4; ++r)
        C[(size_t)(rbase + r) * ldc + col] = (OutT)(acc[rb][nt][r] + bv);
    }
  }
}

// ---------------------------------------------------------------------------
// Flash-style causal MQA attention (all bf16 in ws).
// qkv: [B*S, 2304]; Q at col h*128, K at col 2048, V at col 2176.
// One block per (64 q-rows, head, batch). 4 waves; wave owns 16 q rows.
// ---------------------------------------------------------------------------
__global__ __launch_bounds__(256) void mqa_attn_kernel(
    const bf16_t* __restrict__ qkv, bf16_t* __restrict__ out)
{
  __shared__ bf16_t Ksh[64 * 136];   // K[key][d], padded stride 136
  __shared__ bf16_t VT[128 * 72];    // V^T[d][key], padded stride 72
  __shared__ bf16_t Psh[4 * 16 * 72];// per-wave P[row][key], stride 72

  const int tid  = threadIdx.x;
  const int wave = tid >> 6;
  const int lane = tid & 63;
  const int quad = lane >> 4;
  const int c16  = lane & 15;
  const int qb = blockIdx.x;
  const int h  = blockIdx.y;
  const int b  = blockIdx.z;
  const float scale = 0.08838834764831845f;  // 1/sqrt(128)

  const int qrow = qb * 64 + wave * 16 + c16;
  const bf16_t* qp = qkv + ((size_t)(b * S_LEN + qrow)) * QKVN + h * HD;
  bf16x8 qf[4];
  #pragma unroll
  for (int ks = 0; ks < 4; ++ks) qf[ks] = *(const bf16x8*)(qp + ks * 32 + quad * 8);

  float m_r[4], l_r[4];
  #pragma unroll
  for (int r = 0; r < 4; ++r) { m_r[r] = NEG_BIG; l_r[r] = 0.0f; }
  f32x4 o[8] = {};

  const bf16_t* kbase = qkv + (size_t)b * S_LEN * QKVN + HID;
  const bf16_t* vbase = qkv + (size_t)b * S_LEN * QKVN + HID + HD;
  const int nkt = qb + 1;

  for (int kt = 0; kt < nkt; ++kt) {
    __syncthreads();
    for (int c = tid; c < 1024; c += 256) {
      int key = c >> 4, dc = c & 15;
      *(bf16x8*)(Ksh + key * 136 + dc * 8) =
          *(const bf16x8*)(kbase + (size_t)(kt * 64 + key) * QKVN + dc * 8);
    }
    for (int c = tid; c < 1024; c += 256) {
      int key = c >> 4, dc = c & 15;
      bf16x8 v = *(const bf16x8*)(vbase + (size_t)(kt * 64 + key) * QKVN + dc * 8);
      #pragma unroll
      for (int j = 0; j < 8; ++j) VT[(dc * 8 + j) * 72 + key] = v[j];
    }
    __syncthreads();

    f32x4 sacc[4] = {};
    #pragma unroll
    for (int nt = 0; nt < 4; ++nt) {
      #pragma unroll
      for (int ks = 0; ks < 4; ++ks) {
        bf16x8 kf = *(const bf16x8*)(Ksh + (c16 + nt * 16) * 136 + ks * 32 + quad * 8);
        sacc[nt] = __builtin_amdgcn_mfma_f32_16x16x32_bf16(qf[ks], kf, sacc[nt], 0, 0, 0);
      }
    }

    float s[4][4], mx[4];
    #pragma unroll
    for (int r = 0; r < 4; ++r) mx[r] = NEG_BIG;
    #pragma unroll
    for (int nt = 0; nt < 4; ++nt) {
      int key = kt * 64 + nt * 16 + c16;
      #pragma unroll
      for (int r = 0; r < 4; ++r) {
        int qi = qb * 64 + wave * 16 + quad * 4 + r;
        float v = sacc[nt][r] * scale;
        if (key > qi) v = NEG_BIG;
        s[nt][r] = v;
        mx[r] = fmaxf(mx[r], v);
      }
    }
    #pragma unroll
    for (int off = 1; off < 16; off <<= 1) {
      #pragma unroll
      for (int r = 0; r < 4; ++r) mx[r] = fmaxf(mx[r], __shfl_xor(mx[r], off, 64));
    }

    float alpha[4];
    #pragma unroll
    for (int r = 0; r < 4; ++r) {
      float mn = fmaxf(m_r[r], mx[r]);
      alpha[r] = __expf(m_r[r] - mn);
      m_r[r] = mn;
    }

    float rs[4] = {0.f, 0.f, 0.f, 0.f};
    #pragma unroll
    for (int nt = 0; nt < 4; ++nt) {
      #pragma unroll
      for (int r = 0; r < 4; ++r) {
        float p = __expf(s[nt][r] - m_r[r]);
        s[nt][r] = p;
        rs[r] += p;
      }
    }
    #pragma unroll
    for (int off = 1; off < 16; off <<= 1) {
      #pragma unroll
      for (int r = 0; r < 4; ++r) rs[r] += __shfl_xor(rs[r], off, 64);
    }
    #pragma unroll
    for (int r = 0; r < 4; ++r) l_r[r] = l_r[r] * alpha[r] + rs[r];
    #pragma unroll
    for (int nt = 0; nt < 8; ++nt) {
      #pragma unroll
      for (int r = 0; r < 4; ++r) o[nt][r] *= alpha[r];
    }

    bf16_t* Pw = Psh + wave * 16 * 72;
    #pragma unroll
    for (int nt = 0; nt < 4; ++nt) {
      #pragma unroll
      for (int r = 0; r < 4; ++r)
        Pw[(quad * 4 + r) * 72 + nt * 16 + c16] = (bf16_t)s[nt][r];
    }
    __syncthreads();

    #pragma unroll
    for (int ks = 0; ks < 2; ++ks) {
      bf16x8 pf = *(const bf16x8*)(Pw + c16 * 72 + ks * 32 + quad * 8);
      #pragma unroll
      for (int nt = 0; nt < 8; ++nt) {
        bf16x8 vf = *(const bf16x8*)(VT + (c16 + nt * 16) * 72 + ks * 32 + quad * 8);
        o[nt] = __builtin_amdgcn_mfma_f32_16x16x32_bf16(pf, vf, o[nt], 0, 0, 0);
      }
    }
  }

  #pragma unroll
  for (int r = 0; r < 4; ++r) {
    int qi = qb * 64 + wave * 16 + quad * 4 + r;
    float inv = 1.0f / fmaxf(l_r[r], 1e-20f);   // guard: never inf
    bf16_t* orow = out + ((size_t)(b * S_LEN + qi)) * HID + h * HD;
    #pragma unroll
    for (int nt = 0; nt < 8; ++nt)
      orow[nt * 16 + c16] = (bf16_t)(o[nt][r] * inv);
  }
}

extern "C" void kernel_launch(void* const* d_in, const int* in_sizes, int n_in,
                              void* d_out, int out_size, void* d_ws, size_t ws_size,
                              hipStream_t stream) {
  // fp32 I/O per the reference dtypes; bf16 internal compute.
  const float* hidden_f   = (const float*)d_in[0];
  // d_in[1] = attention_mask (causal, deterministic) -- ignored
  const float* c_attn_w_f = (const float*)d_in[2];
  const float* c_attn_b_f = (const float*)d_in[3];
  const float* c_proj_w_f = (const float*)d_in[4];
  const float* c_proj_b_f = (const float*)d_in[5];
  float* out = (float*)d_out;

  const int M = 2 * S_LEN;                 // 4096 rows
  const int nH  = M * HID;                 // 8,388,608
  const int nWq = HID * QKVN;              // 4,718,592
  const int nWp = HID * HID;               // 4,194,304

  bf16_t* hbf   = (bf16_t*)d_ws;           // bf16 hidden
  bf16_t* wqkv  = hbf  + nH;
  bf16_t* wproj = wqkv + nWq;
  bf16_t* qkv   = wproj + nWp;             // 4096 x 2304
  bf16_t* attn  = qkv  + (size_t)M * QKVN; // 4096 x 2048

  // 0) downcast inputs
  cvt_f32_bf16_kernel<<<nH  / 1024, 256, 0, stream>>>(hidden_f,   hbf,   nH);
  cvt_f32_bf16_kernel<<<nWq / 1024, 256, 0, stream>>>(c_attn_w_f, wqkv,  nWq);
  cvt_f32_bf16_kernel<<<nWp / 1024, 256, 0, stream>>>(c_proj_w_f, wproj, nWp);

  // 1) QKV = hidden @ c_attn_w + c_attn_b   (bf16 out)
  dim3 g1(QKVN / 128, M / 128);
  gemm_bias_kernel<bf16_t><<<g1, 256, 0, stream>>>(hbf, wqkv, c_attn_b_f, qkv,
                                                   HID, HID, QKVN, QKVN);

  // 2) causal MQA attention (bf16 out)
  dim3 g2(S_LEN / 64, NH, 2);
  mqa_attn_kernel<<<g2, 256, 0, stream>>>(qkv, attn);

  // 3) out = attn @ c_proj_w + c_proj_b    (fp32 out)
  dim3 g3(HID / 128, M / 128);
  gemm_bias_kernel<float><<<g3, 256, 0, stream>>>(attn, wproj, c_proj_b_f, out,
                                                  HID, HID, HID, HID);
}

// Round 3
// 445.675 us; speedup vs baseline: 2.0360x; 2.0360x over previous
//
#include <hip/hip_runtime.h>
#include <hip/hip_bf16.h>

typedef __bf16 bf16_t;
typedef __bf16 bf16x8 __attribute__((ext_vector_type(8)));
typedef __bf16 bf16x4 __attribute__((ext_vector_type(4)));
typedef float f32x4 __attribute__((ext_vector_type(4)));

#define S_LEN 2048
#define HID   2048
#define NH    16
#define HD    128
#define QKVN  2304   // 2048 + 2*128
#define NEG_BIG (-30000.0f)

// ---------------------------------------------------------------------------
// fp32 -> bf16 downcast, float4-vectorized.
// ---------------------------------------------------------------------------
__global__ __launch_bounds__(256) void cvt_f32_bf16_kernel(
    const float* __restrict__ in, bf16_t* __restrict__ out, int n)
{
  int i = (blockIdx.x * 256 + threadIdx.x) * 4;
  if (i < n) {
    float4 v = *(const float4*)(in + i);
    bf16x4 o;
    o[0] = (bf16_t)v.x; o[1] = (bf16_t)v.y; o[2] = (bf16_t)v.z; o[3] = (bf16_t)v.w;
    *(bf16x4*)(out + i) = o;
  }
}

// ---------------------------------------------------------------------------
// fp32 W[K][N] -> bf16 WT[N][K]. Reads coalesced across n (64 lanes x 4B),
// one bf16x8 vector write per thread.
// ---------------------------------------------------------------------------
__global__ __launch_bounds__(256) void transpose_cvt_kernel(
    const float* __restrict__ in, bf16_t* __restrict__ out, int K, int N)
{
  int nc = threadIdx.x & 63;
  int kg = threadIdx.x >> 6;                 // 0..3
  int n  = blockIdx.x * 64 + nc;
  int kb = blockIdx.y * 32 + kg * 8;
  bf16x8 v;
  #pragma unroll
  for (int i = 0; i < 8; ++i) v[i] = (bf16_t)in[(size_t)(kb + i) * N + n];
  *(bf16x8*)(out + (size_t)n * K + kb) = v;
}

// ---------------------------------------------------------------------------
// Extract V^T from qkv: vtg[b][d][s] = qkv[b*S+s][2176+d]. Reads coalesced
// across d; one bf16x8 write per thread.
// ---------------------------------------------------------------------------
__global__ __launch_bounds__(256) void vt_extract_kernel(
    const bf16_t* __restrict__ qkv, bf16_t* __restrict__ vtg)
{
  int d  = threadIdx.x & 127;
  int sg = threadIdx.x >> 7;                 // 0..1
  int b  = blockIdx.y;
  int s8 = blockIdx.x * 2 + sg;
  bf16x8 v;
  #pragma unroll
  for (int i = 0; i < 8; ++i)
    v[i] = qkv[((size_t)(b * S_LEN + s8 * 8 + i)) * QKVN + HID + HD + d];
  *(bf16x8*)(vtg + ((size_t)(b * HD + d)) * S_LEN + s8 * 8) = v;
}

// ---------------------------------------------------------------------------
// GEMM: C[M,N] = A[M,K] @ W[K,N] + bias, with W supplied pre-transposed as
// WT[N][K]. 128x128 tile, BK=32, 4 waves. WT tile staged in LDS with
// vectorized writes (no transpose in LDS -> no 16-way conflicts).
// ---------------------------------------------------------------------------
template <typename OutT>
__global__ __launch_bounds__(256) void gemm_bias_kernel(
    const bf16_t* __restrict__ A, const bf16_t* __restrict__ WT,
    const float* __restrict__ bias, OutT* __restrict__ C,
    int K, int lda, int ldc)
{
  __shared__ bf16_t WTsh[128 * 40];          // WTsh[n][k], stride 40 (bank +20dw)

  const int tid  = threadIdx.x;
  const int wave = tid >> 6;
  const int lane = tid & 63;
  const int quad = lane >> 4;
  const int c16  = lane & 15;
  const int n0 = blockIdx.x * 128;
  const int m0 = blockIdx.y * 128;

  f32x4 acc[2][8] = {};

  for (int k0 = 0; k0 < K; k0 += 32) {
    __syncthreads();
    for (int c = tid; c < 512; c += 256) {
      int n = c >> 2, kc = c & 3;
      *(bf16x8*)(WTsh + n * 40 + kc * 8) =
          *(const bf16x8*)(WT + (size_t)(n0 + n) * K + k0 + kc * 8);
    }
    __syncthreads();

    bf16x8 af[2];
    #pragma unroll
    for (int rb = 0; rb < 2; ++rb)
      af[rb] = *(const bf16x8*)(A + (size_t)(m0 + wave * 32 + rb * 16 + c16) * lda
                                 + k0 + quad * 8);
    #pragma unroll
    for (int nt = 0; nt < 8; ++nt) {
      bf16x8 bfrag = *(const bf16x8*)(WTsh + (c16 + nt * 16) * 40 + quad * 8);
      acc[0][nt] = __builtin_amdgcn_mfma_f32_16x16x32_bf16(af[0], bfrag, acc[0][nt], 0, 0, 0);
      acc[1][nt] = __builtin_amdgcn_mfma_f32_16x16x32_bf16(af[1], bfrag, acc[1][nt], 0, 0, 0);
    }
  }

  #pragma unroll
  for (int nt = 0; nt < 8; ++nt) {
    int col = n0 + nt * 16 + c16;
    float bv = bias[col];
    #pragma unroll
    for (int rb = 0; rb < 2; ++rb) {
      int rbase = m0 + wave * 32 + rb * 16 + quad * 4;
      #pragma unroll
      for (int r = 0; r < 4; ++r)
        C[(size_t)(rbase + r) * ldc + col] = (OutT)(acc[rb][nt][r] + bv);
    }
  }
}

// ---------------------------------------------------------------------------
// Causal MQA attention, S^T formulation:
//   S^T = K · Q^T   (A = K rows from LDS natural, B = Q rows from global)
//   O^T = V^T · P^T (A = V^T rows from pre-transposed global via LDS,
//                    B = P^T built in-register via ds_bpermute shuffles)
// Per-lane softmax state (q = lane&15): 2 shuffle steps, no P LDS round-trip,
// one barrier per key-tile. Fold: block does q-tiles {qb, 31-qb} -> uniform
// 33 key-tiles per block.
// ---------------------------------------------------------------------------
__global__ __launch_bounds__(256) void mqa_attn_kernel(
    const bf16_t* __restrict__ qkv, const bf16_t* __restrict__ vtg,
    bf16_t* __restrict__ out)
{
  __shared__ bf16_t Ksh[64 * 136];   // K[key][d]  (also reused as O scratch)
  __shared__ bf16_t VTsh[128 * 72];  // V^T[d][key]

  const int tid  = threadIdx.x;
  const int wave = tid >> 6;
  const int lane = tid & 63;
  const int quad = lane >> 4;
  const int c16  = lane & 15;
  const int h = blockIdx.y;
  const int b = blockIdx.z;
  const float scale = 0.08838834764831845f;  // 1/sqrt(128)

  const bf16_t* kbase = qkv + (size_t)b * S_LEN * QKVN + HID;
  const bf16_t* vtb   = vtg + (size_t)b * HD * S_LEN;

  for (int half = 0; half < 2; ++half) {
    const int qb = half ? (31 - (int)blockIdx.x) : (int)blockIdx.x;
    const int q0 = qb * 64;
    const int qrow = q0 + wave * 16 + c16;

    // Q fragment (B-operand: n = c16 = qrow, k contiguous), pre-scaled
    const bf16_t* qp = qkv + ((size_t)(b * S_LEN + qrow)) * QKVN + h * HD;
    bf16x8 qf[4];
    #pragma unroll
    for (int ks = 0; ks < 4; ++ks) {
      bf16x8 t = *(const bf16x8*)(qp + ks * 32 + quad * 8);
      #pragma unroll
      for (int j = 0; j < 8; ++j) t[j] = (bf16_t)((float)t[j] * scale);
      qf[ks] = t;
    }

    float m_q = NEG_BIG, l_q = 0.0f;
    f32x4 o[8] = {};

    for (int kt = 0; kt <= qb; ++kt) {
      __syncthreads();
      // stage K tile (64 keys x 128 d), natural layout, vector writes
      for (int c = tid; c < 1024; c += 256) {
        int key = c >> 4, dc = c & 15;
        *(bf16x8*)(Ksh + key * 136 + dc * 8) =
            *(const bf16x8*)(kbase + (size_t)(kt * 64 + key) * QKVN + dc * 8);
      }
      // stage V^T tile (128 d x 64 keys), natural layout, vector writes
      for (int c = tid; c < 1024; c += 256) {
        int d = c >> 3, kc = c & 7;
        *(bf16x8*)(VTsh + d * 72 + kc * 8) =
            *(const bf16x8*)(vtb + (size_t)d * S_LEN + kt * 64 + kc * 8);
      }
      __syncthreads();

      // S^T[key][q]: sacc[mt] holds keys mt*16+quad*4+r, q = c16
      f32x4 sacc[4] = {};
      #pragma unroll
      for (int mt = 0; mt < 4; ++mt) {
        #pragma unroll
        for (int ks = 0; ks < 4; ++ks) {
          bf16x8 kf = *(const bf16x8*)(Ksh + (mt * 16 + c16) * 136 + ks * 32 + quad * 8);
          sacc[mt] = __builtin_amdgcn_mfma_f32_16x16x32_bf16(kf, qf[ks], sacc[mt], 0, 0, 0);
        }
      }

      float p[4][4];
      float mx = NEG_BIG;
      if (kt == qb) {   // diagonal tile: apply causal mask
        #pragma unroll
        for (int mt = 0; mt < 4; ++mt) {
          #pragma unroll
          for (int r = 0; r < 4; ++r) {
            int key = kt * 64 + mt * 16 + quad * 4 + r;
            float v = sacc[mt][r];
            if (key > qrow) v = NEG_BIG;
            p[mt][r] = v;
            mx = fmaxf(mx, v);
          }
        }
      } else {
        #pragma unroll
        for (int mt = 0; mt < 4; ++mt) {
          #pragma unroll
          for (int r = 0; r < 4; ++r) {
            p[mt][r] = sacc[mt][r];
            mx = fmaxf(mx, sacc[mt][r]);
          }
        }
      }
      mx = fmaxf(mx, __shfl_xor(mx, 16));
      mx = fmaxf(mx, __shfl_xor(mx, 32));

      float mn = fmaxf(m_q, mx);
      float alpha = __expf(m_q - mn);
      m_q = mn;

      float rs = 0.f;
      #pragma unroll
      for (int mt = 0; mt < 4; ++mt) {
        #pragma unroll
        for (int r = 0; r < 4; ++r) {
          float pe = __expf(p[mt][r] - m_q);
          p[mt][r] = pe;
          rs += pe;
        }
      }
      rs += __shfl_xor(rs, 16);
      rs += __shfl_xor(rs, 32);
      l_q = l_q * alpha + rs;
      #pragma unroll
      for (int mt8 = 0; mt8 < 8; ++mt8) {
        #pragma unroll
        for (int r = 0; r < 4; ++r) o[mt8][r] *= alpha;
      }

      // P^T (C-layout regs) -> B-fragment layout via shuffles.
      // B-frag elem j of lane(quad,c16) = P^T[key = kh*32+quad*8+j][q = c16],
      // which lives at lane (quad_src*16+c16), reg p[2kh + (quad>>1)][j&3].
      bf16x8 pf[2];
      #pragma unroll
      for (int kh = 0; kh < 2; ++kh) {
        #pragma unroll
        for (int j = 0; j < 8; ++j) {
          int quad_src = (2 * quad + (j >> 2)) & 3;
          int src_lane = quad_src * 16 + c16;
          float v0 = __shfl(p[2 * kh][j & 3], src_lane);
          float v1 = __shfl(p[2 * kh + 1][j & 3], src_lane);
          pf[kh][j] = (bf16_t)(quad < 2 ? v0 : v1);
        }
      }

      // O^T += V^T · P^T : o[mt8] holds d = mt8*16+quad*4+r, q = c16
      #pragma unroll
      for (int mt8 = 0; mt8 < 8; ++mt8) {
        #pragma unroll
        for (int kh = 0; kh < 2; ++kh) {
          bf16x8 vf = *(const bf16x8*)(VTsh + (mt8 * 16 + c16) * 72 + kh * 32 + quad * 8);
          o[mt8] = __builtin_amdgcn_mfma_f32_16x16x32_bf16(vf, pf[kh], o[mt8], 0, 0, 0);
        }
      }
    }

    // epilogue: normalize, transpose O^T -> O via LDS (reuse Ksh), store
    float inv = 1.0f / fmaxf(l_q, 1e-20f);
    __syncthreads();                       // all waves done with Ksh/VTsh
    bf16_t* Osh = Ksh + wave * 16 * 136;   // per-wave 16 rows x 128 d
    #pragma unroll
    for (int mt8 = 0; mt8 < 8; ++mt8) {
      #pragma unroll
      for (int r = 0; r < 4; ++r)
        Osh[c16 * 136 + mt8 * 16 + quad * 4 + r] = (bf16_t)(o[mt8][r] * inv);
    }
    __syncthreads();
    int ql = lane >> 2, dc = lane & 3;
    #pragma unroll
    for (int i = 0; i < 4; ++i) {
      bf16x8 v = *(const bf16x8*)(Osh + ql * 136 + dc * 8 + i * 32);
      *(bf16x8*)(out + ((size_t)(b * S_LEN + q0 + wave * 16 + ql)) * HID
                     + h * HD + dc * 8 + i * 32) = v;
    }
  }
}

extern "C" void kernel_launch(void* const* d_in, const int* in_sizes, int n_in,
                              void* d_out, int out_size, void* d_ws, size_t ws_size,
                              hipStream_t stream) {
  const float* hidden_f   = (const float*)d_in[0];
  // d_in[1] = attention_mask (deterministic causal) -- ignored
  const float* c_attn_w_f = (const float*)d_in[2];
  const float* c_attn_b_f = (const float*)d_in[3];
  const float* c_proj_w_f = (const float*)d_in[4];
  const float* c_proj_b_f = (const float*)d_in[5];
  float* out = (float*)d_out;

  const int M = 2 * S_LEN;                 // 4096
  const int nH  = M * HID;                 // 8,388,608
  const int nWq = HID * QKVN;              // 4,718,592
  const int nWp = HID * HID;               // 4,194,304

  bf16_t* hbf   = (bf16_t*)d_ws;
  bf16_t* wqT   = hbf  + nH;               // WT_qkv [2304][2048]
  bf16_t* wpT   = wqT  + nWq;              // WT_proj[2048][2048]
  bf16_t* qkv   = wpT  + nWp;              // [4096][2304]
  bf16_t* attn  = qkv  + (size_t)M * QKVN; // [4096][2048]
  bf16_t* vtg   = attn + (size_t)M * HID;  // V^T [2][128][2048]

  // 0) convert hidden; convert+transpose weights
  cvt_f32_bf16_kernel<<<nH / 1024, 256, 0, stream>>>(hidden_f, hbf, nH);
  dim3 gt1(QKVN / 64, HID / 32);
  transpose_cvt_kernel<<<gt1, 256, 0, stream>>>(c_attn_w_f, wqT, HID, QKVN);
  dim3 gt2(HID / 64, HID / 32);
  transpose_cvt_kernel<<<gt2, 256, 0, stream>>>(c_proj_w_f, wpT, HID, HID);

  // 1) QKV GEMM
  dim3 g1(QKVN / 128, M / 128);
  gemm_bias_kernel<bf16_t><<<g1, 256, 0, stream>>>(hbf, wqT, c_attn_b_f, qkv,
                                                   HID, HID, QKVN);

  // 1b) extract V^T
  dim3 gv(S_LEN / 16, 2);
  vt_extract_kernel<<<gv, 256, 0, stream>>>(qkv, vtg);

  // 2) attention (folded causal schedule)
  dim3 g2(16, NH, 2);
  mqa_attn_kernel<<<g2, 256, 0, stream>>>(qkv, vtg, attn);

  // 3) proj GEMM (fp32 out)
  dim3 g3(HID / 128, M / 128);
  gemm_bias_kernel<float><<<g3, 256, 0, stream>>>(attn, wpT, c_proj_b_f, out,
                                                  HID, HID, HID);
}

// Round 4
// 352.350 us; speedup vs baseline: 2.5753x; 1.2649x over previous
//
#include <hip/hip_runtime.h>
#include <hip/hip_bf16.h>

typedef __bf16 bf16_t;
typedef __bf16 bf16x8 __attribute__((ext_vector_type(8)));
typedef __bf16 bf16x4 __attribute__((ext_vector_type(4)));
typedef float f32x4 __attribute__((ext_vector_type(4)));

#define S_LEN 2048
#define HID   2048
#define NH    16
#define HD    128
#define QKVN  2304   // 2048 + 2*128
#define NEG_BIG (-30000.0f)

// direct global->LDS DMA, 16B per lane. lds dst must be the WAVE-UNIFORM base;
// HW adds lane*16 itself (m104). No LDS padding allowed in the covered range.
__device__ __forceinline__ void gld_lds16(const bf16_t* g, bf16_t* l) {
  __builtin_amdgcn_global_load_lds(
      (const __attribute__((address_space(1))) void*)((const void*)g),
      (__attribute__((address_space(3))) void*)((void*)l), 16, 0, 0);
}

// ---------------------------------------------------------------------------
// fp32 -> bf16 downcast, float4-vectorized.
// ---------------------------------------------------------------------------
__global__ __launch_bounds__(256) void cvt_f32_bf16_kernel(
    const float* __restrict__ in, bf16_t* __restrict__ out, int n)
{
  int i = (blockIdx.x * 256 + threadIdx.x) * 4;
  if (i < n) {
    float4 v = *(const float4*)(in + i);
    bf16x4 o;
    o[0] = (bf16_t)v.x; o[1] = (bf16_t)v.y; o[2] = (bf16_t)v.z; o[3] = (bf16_t)v.w;
    *(bf16x4*)(out + i) = o;
  }
}

// ---------------------------------------------------------------------------
// fp32 W[K][N] -> bf16 WT[N][K].
// ---------------------------------------------------------------------------
__global__ __launch_bounds__(256) void transpose_cvt_kernel(
    const float* __restrict__ in, bf16_t* __restrict__ out, int K, int N)
{
  int nc = threadIdx.x & 63;
  int kg = threadIdx.x >> 6;
  int n  = blockIdx.x * 64 + nc;
  int kb = blockIdx.y * 32 + kg * 8;
  bf16x8 v;
  #pragma unroll
  for (int i = 0; i < 8; ++i) v[i] = (bf16_t)in[(size_t)(kb + i) * N + n];
  *(bf16x8*)(out + (size_t)n * K + kb) = v;
}

// ---------------------------------------------------------------------------
// Extract V^T from qkv: vtg[b][d][s] = qkv[b*S+s][2176+d].
// ---------------------------------------------------------------------------
__global__ __launch_bounds__(256) void vt_extract_kernel(
    const bf16_t* __restrict__ qkv, bf16_t* __restrict__ vtg)
{
  int d  = threadIdx.x & 127;
  int sg = threadIdx.x >> 7;
  int b  = blockIdx.y;
  int s8 = blockIdx.x * 2 + sg;
  bf16x8 v;
  #pragma unroll
  for (int i = 0; i < 8; ++i)
    v[i] = qkv[((size_t)(b * S_LEN + s8 * 8 + i)) * QKVN + HID + HD + d];
  *(bf16x8*)(vtg + ((size_t)(b * HD + d)) * S_LEN + s8 * 8) = v;
}

// ---------------------------------------------------------------------------
// GEMM: C[M,N] = A[M,K] @ WT^T + bias (WT pre-transposed [N][K]).
// 128x128 tile, BK=32, 4 waves. WT tile staged via global_load_lds (16B),
// unpadded stride-32 LDS (DMA requires contiguity; read pattern is
// bank-balanced: banks 16*(c16&1)+4*quad, 8 lanes/4-bank group = min phases).
// A fragments prefetched one K-step ahead.
// ---------------------------------------------------------------------------
template <typename OutT>
__global__ __launch_bounds__(256) void gemm_bias_kernel(
    const bf16_t* __restrict__ A, const bf16_t* __restrict__ WT,
    const float* __restrict__ bias, OutT* __restrict__ C,
    int K, int lda, int ldc)
{
  __shared__ bf16_t WTsh[128 * 32];   // [n][k], NO padding (lds-dma)

  const int tid  = threadIdx.x;
  const int wave = tid >> 6;
  const int lane = tid & 63;
  const int quad = lane >> 4;
  const int c16  = lane & 15;
  const int n0 = blockIdx.x * 128;
  const int m0 = blockIdx.y * 128;

  f32x4 acc[2][8] = {};

  bf16x8 af[2], afn[2];
  #pragma unroll
  for (int rb = 0; rb < 2; ++rb)
    af[rb] = *(const bf16x8*)(A + (size_t)(m0 + wave * 32 + rb * 16 + c16) * lda
                               + quad * 8);

  for (int k0 = 0; k0 < K; k0 += 32) {
    __syncthreads();
    #pragma unroll
    for (int j = 0; j < 2; ++j) {
      int q = (wave * 2 + j) * 64 + lane;      // 16B-chunk id, 0..511
      int n = q >> 2, kc = q & 3;
      gld_lds16(WT + (size_t)(n0 + n) * K + k0 + kc * 8,
                WTsh + (wave * 2 + j) * 512);  // uniform base; +lane*16B by HW
    }
    __syncthreads();

    int kn = (k0 + 32 < K) ? k0 + 32 : 0;      // prefetch next A frags
    #pragma unroll
    for (int rb = 0; rb < 2; ++rb)
      afn[rb] = *(const bf16x8*)(A + (size_t)(m0 + wave * 32 + rb * 16 + c16) * lda
                                  + kn + quad * 8);

    #pragma unroll
    for (int nt = 0; nt < 8; ++nt) {
      bf16x8 bfrag = *(const bf16x8*)(WTsh + (c16 + nt * 16) * 32 + quad * 8);
      acc[0][nt] = __builtin_amdgcn_mfma_f32_16x16x32_bf16(af[0], bfrag, acc[0][nt], 0, 0, 0);
      acc[1][nt] = __builtin_amdgcn_mfma_f32_16x16x32_bf16(af[1], bfrag, acc[1][nt], 0, 0, 0);
    }
    af[0] = afn[0]; af[1] = afn[1];
  }

  #pragma unroll
  for (int nt = 0; nt < 8; ++nt) {
    int col = n0 + nt * 16 + c16;
    float bv = bias[col];
    #pragma unroll
    for (int rb = 0; rb < 2; ++rb) {
      int rbase = m0 + wave * 32 + rb * 16 + quad * 4;
      #pragma unroll
      for (int r = 0; r < 4; ++r)
        C[(size_t)(rbase + r) * ldc + col] = (OutT)(acc[rb][nt][r] + bv);
    }
  }
}

// ---------------------------------------------------------------------------
// Causal MQA attention, S^T formulation, 8 waves / 512 threads.
// Two 4-wave groups split the key tiles by parity (g = wave>>2 takes
// kt = 2*ss+g) over the SAME 64-row q-tile; partial (m,l,O^T) merged via LDS
// at the end. Folded q-tile pairs {bx, 31-bx} -> uniform 17 supersteps.
// P-transform: C-layout regs -> packed b64 stores into the (dead) K-tile LDS
// region as P[q][key] -> 2 ds_read_b128 B-fragments. No bpermutes.
// Softmax in exp2 domain (scale*log2e folded into Q).
// ---------------------------------------------------------------------------
__global__ __launch_bounds__(512, 4) void mqa_attn_kernel(
    const bf16_t* __restrict__ qkv, const bf16_t* __restrict__ vtg,
    bf16_t* __restrict__ out)
{
  __shared__ bf16_t Ksh[2][64 * 136];   // per-group K tile / P scratch / O scratch
  __shared__ bf16_t VTsh[2][128 * 72];  // per-group V^T tile / f32 combine scratch

  const int tid  = threadIdx.x;
  const int wave = tid >> 6;
  const int g    = wave >> 2;        // key-parity group
  const int wv   = wave & 3;         // q-strip within tile
  const int lane = tid & 63;
  const int quad = lane >> 4;
  const int c16  = lane & 15;
  const int gt   = tid & 255;        // thread id within group
  const int h = blockIdx.y;
  const int b = blockIdx.z;
  const float qscale = 0.08838834764831845f * 1.4426950408889634f; // /sqrt(128)*log2e

  const bf16_t* kbase = qkv + (size_t)b * S_LEN * QKVN + HID;
  const bf16_t* vtb   = vtg + (size_t)b * HD * S_LEN;

  for (int half = 0; half < 2; ++half) {
    const int qb = half ? (31 - (int)blockIdx.x) : (int)blockIdx.x;
    const int q0 = qb * 64;
    const int qrow = q0 + wv * 16 + c16;

    const bf16_t* qp = qkv + ((size_t)(b * S_LEN + qrow)) * QKVN + h * HD;
    bf16x8 qf[4];
    #pragma unroll
    for (int ks = 0; ks < 4; ++ks) {
      bf16x8 t = *(const bf16x8*)(qp + ks * 32 + quad * 8);
      #pragma unroll
      for (int j = 0; j < 8; ++j) t[j] = (bf16_t)((float)t[j] * qscale);
      qf[ks] = t;
    }

    float m_q = NEG_BIG, l_q = 0.0f;
    f32x4 o[8] = {};
    const int nss = (qb + 2) >> 1;   // uniform across block (both groups)

    for (int ss = 0; ss < nss; ++ss) {
      const int kt = 2 * ss + g;
      const bool active = (kt <= qb);

      __syncthreads();
      if (active) {
        for (int c = gt; c < 1024; c += 256) {
          int key = c >> 4, dc = c & 15;
          *(bf16x8*)(&Ksh[g][key * 136 + dc * 8]) =
              *(const bf16x8*)(kbase + (size_t)(kt * 64 + key) * QKVN + dc * 8);
        }
        for (int c = gt; c < 1024; c += 256) {
          int d = c >> 3, kc = c & 7;
          *(bf16x8*)(&VTsh[g][d * 72 + kc * 8]) =
              *(const bf16x8*)(vtb + (size_t)d * S_LEN + kt * 64 + kc * 8);
        }
      }
      __syncthreads();

      float p[4][4];
      if (active) {
        f32x4 sacc[4] = {};
        #pragma unroll
        for (int mt = 0; mt < 4; ++mt) {
          #pragma unroll
          for (int ks = 0; ks < 4; ++ks) {
            bf16x8 kf = *(const bf16x8*)(&Ksh[g][(mt * 16 + c16) * 136 + ks * 32 + quad * 8]);
            sacc[mt] = __builtin_amdgcn_mfma_f32_16x16x32_bf16(kf, qf[ks], sacc[mt], 0, 0, 0);
          }
        }
        float mx = NEG_BIG;
        if (kt == qb) {
          #pragma unroll
          for (int mt = 0; mt < 4; ++mt) {
            #pragma unroll
            for (int r = 0; r < 4; ++r) {
              int key = kt * 64 + mt * 16 + quad * 4 + r;
              float v = sacc[mt][r];
              if (key > qrow) v = NEG_BIG;
              p[mt][r] = v;
              mx = fmaxf(mx, v);
            }
          }
        } else {
          #pragma unroll
          for (int mt = 0; mt < 4; ++mt) {
            #pragma unroll
            for (int r = 0; r < 4; ++r) {
              p[mt][r] = sacc[mt][r];
              mx = fmaxf(mx, sacc[mt][r]);
            }
          }
        }
        mx = fmaxf(mx, __shfl_xor(mx, 16));
        mx = fmaxf(mx, __shfl_xor(mx, 32));

        float mn = fmaxf(m_q, mx);
        float alpha = __builtin_exp2f(m_q - mn);
        m_q = mn;

        float rs = 0.f;
        #pragma unroll
        for (int mt = 0; mt < 4; ++mt) {
          #pragma unroll
          for (int r = 0; r < 4; ++r) {
            float pe = __builtin_exp2f(p[mt][r] - m_q);
            p[mt][r] = pe;
            rs += pe;
          }
        }
        rs += __shfl_xor(rs, 16);
        rs += __shfl_xor(rs, 32);
        l_q = l_q * alpha + rs;
        #pragma unroll
        for (int mt8 = 0; mt8 < 8; ++mt8) {
          #pragma unroll
          for (int r = 0; r < 4; ++r) o[mt8][r] *= alpha;
        }
      }

      __syncthreads();   // all K-tile reads done -> Ksh[g] reusable for P
      if (active) {
        bf16_t* Pw = &Ksh[g][(wv * 16) * 136];  // wave slice: P[q=c16][key]
        #pragma unroll
        for (int mt = 0; mt < 4; ++mt) {
          bf16x4 pk;
          #pragma unroll
          for (int r = 0; r < 4; ++r) pk[r] = (bf16_t)p[mt][r];
          *(bf16x4*)(Pw + c16 * 136 + mt * 16 + quad * 4) = pk;
        }
        bf16x8 pf[2];
        #pragma unroll
        for (int kh = 0; kh < 2; ++kh)
          pf[kh] = *(const bf16x8*)(Pw + c16 * 136 + kh * 32 + quad * 8);
        #pragma unroll
        for (int mt8 = 0; mt8 < 8; ++mt8) {
          #pragma unroll
          for (int kh = 0; kh < 2; ++kh) {
            bf16x8 vf = *(const bf16x8*)(&VTsh[g][(mt8 * 16 + c16) * 72 + kh * 32 + quad * 8]);
            o[mt8] = __builtin_amdgcn_mfma_f32_16x16x32_bf16(vf, pf[kh], o[mt8], 0, 0, 0);
          }
        }
      }
    }

    // ---- merge parity groups ----
    __syncthreads();                       // all PV reads done (VTsh dead)
    float* scr = (float*)&VTsh[0][0];      // [wv][q=c16][d] stride 132
    float* mls = scr + 4 * 16 * 132;
    if (g == 1) {
      float* op = scr + (wv * 16 + c16) * 132;
      #pragma unroll
      for (int mt8 = 0; mt8 < 8; ++mt8)
        *(f32x4*)(op + mt8 * 16 + quad * 4) = o[mt8];
      if (quad == 0) {
        mls[wv * 32 + c16] = m_q;
        mls[wv * 32 + 16 + c16] = l_q;
      }
    }
    __syncthreads();
    if (g == 0) {
      float m1 = mls[wv * 32 + c16];
      float l1 = mls[wv * 32 + 16 + c16];
      float mF = fmaxf(m_q, m1);
      float a0 = __builtin_exp2f(m_q - mF);
      float a1 = __builtin_exp2f(m1 - mF);
      float inv = 1.0f / fmaxf(a0 * l_q + a1 * l1, 1e-20f);
      a0 *= inv; a1 *= inv;
      const float* op = scr + (wv * 16 + c16) * 132;
      bf16_t* Osh = &Ksh[0][(wv * 16) * 136];   // per-wave O[q_local][d]
      #pragma unroll
      for (int mt8 = 0; mt8 < 8; ++mt8) {
        f32x4 o1 = *(const f32x4*)(op + mt8 * 16 + quad * 4);
        bf16x4 pk;
        #pragma unroll
        for (int r = 0; r < 4; ++r) pk[r] = (bf16_t)(o[mt8][r] * a0 + o1[r] * a1);
        *(bf16x4*)(Osh + c16 * 136 + mt8 * 16 + quad * 4) = pk;
      }
      int ql = lane >> 2, dc = lane & 3;
      #pragma unroll
      for (int i = 0; i < 4; ++i) {
        bf16x8 v = *(const bf16x8*)(Osh + ql * 136 + dc * 8 + i * 32);
        *(bf16x8*)(out + ((size_t)(b * S_LEN + q0 + wv * 16 + ql)) * HID
                       + h * HD + dc * 8 + i * 32) = v;
      }
    }
  }
}

extern "C" void kernel_launch(void* const* d_in, const int* in_sizes, int n_in,
                              void* d_out, int out_size, void* d_ws, size_t ws_size,
                              hipStream_t stream) {
  const float* hidden_f   = (const float*)d_in[0];
  // d_in[1] = attention_mask (deterministic causal) -- ignored
  const float* c_attn_w_f = (const float*)d_in[2];
  const float* c_attn_b_f = (const float*)d_in[3];
  const float* c_proj_w_f = (const float*)d_in[4];
  const float* c_proj_b_f = (const float*)d_in[5];
  float* out = (float*)d_out;

  const int M = 2 * S_LEN;                 // 4096
  const int nH  = M * HID;
  const int nWq = HID * QKVN;
  const int nWp = HID * HID;

  bf16_t* hbf   = (bf16_t*)d_ws;
  bf16_t* wqT   = hbf  + nH;               // WT_qkv [2304][2048]
  bf16_t* wpT   = wqT  + nWq;              // WT_proj[2048][2048]
  bf16_t* qkv   = wpT  + nWp;              // [4096][2304]
  bf16_t* attn  = qkv  + (size_t)M * QKVN; // [4096][2048]
  bf16_t* vtg   = attn + (size_t)M * HID;  // V^T [2][128][2048]

  cvt_f32_bf16_kernel<<<nH / 1024, 256, 0, stream>>>(hidden_f, hbf, nH);
  dim3 gt1(QKVN / 64, HID / 32);
  transpose_cvt_kernel<<<gt1, 256, 0, stream>>>(c_attn_w_f, wqT, HID, QKVN);
  dim3 gt2(HID / 64, HID / 32);
  transpose_cvt_kernel<<<gt2, 256, 0, stream>>>(c_proj_w_f, wpT, HID, HID);

  dim3 g1(QKVN / 128, M / 128);
  gemm_bias_kernel<bf16_t><<<g1, 256, 0, stream>>>(hbf, wqT, c_attn_b_f, qkv,
                                                   HID, HID, QKVN);

  dim3 gv(S_LEN / 16, 2);
  vt_extract_kernel<<<gv, 256, 0, stream>>>(qkv, vtg);

  dim3 g2(16, NH, 2);
  mqa_attn_kernel<<<g2, 512, 0, stream>>>(qkv, vtg, attn);

  dim3 g3(HID / 128, M / 128);
  gemm_bias_kernel<float><<<g3, 256, 0, stream>>>(attn, wpT, c_proj_b_f, out,
                                                  HID, HID, HID);
}

// Round 5
// 343.485 us; speedup vs baseline: 2.6418x; 1.0258x over previous
//
#include <hip/hip_runtime.h>
#include <hip/hip_bf16.h>

typedef __bf16 bf16_t;
typedef __bf16 bf16x8 __attribute__((ext_vector_type(8)));
typedef __bf16 bf16x4 __attribute__((ext_vector_type(4)));
typedef float f32x4 __attribute__((ext_vector_type(4)));

#define S_LEN 2048
#define HID   2048
#define NH    16
#define HD    128
#define QKVN  2304   // 2048 + 2*128
#define NEG_BIG (-30000.0f)

// direct global->LDS DMA, 16B per lane. lds dst must be the WAVE-UNIFORM base;
// HW adds lane*16 itself (m104). No LDS padding allowed in the covered range.
__device__ __forceinline__ void gld_lds16(const bf16_t* g, bf16_t* l) {
  __builtin_amdgcn_global_load_lds(
      (const __attribute__((address_space(1))) void*)((const void*)g),
      (__attribute__((address_space(3))) void*)((void*)l), 16, 0, 0);
}

// ---------------------------------------------------------------------------
// fp32 -> bf16 downcast, float4-vectorized.
// ---------------------------------------------------------------------------
__global__ __launch_bounds__(256) void cvt_f32_bf16_kernel(
    const float* __restrict__ in, bf16_t* __restrict__ out, int n)
{
  int i = (blockIdx.x * 256 + threadIdx.x) * 4;
  if (i < n) {
    float4 v = *(const float4*)(in + i);
    bf16x4 o;
    o[0] = (bf16_t)v.x; o[1] = (bf16_t)v.y; o[2] = (bf16_t)v.z; o[3] = (bf16_t)v.w;
    *(bf16x4*)(out + i) = o;
  }
}

// ---------------------------------------------------------------------------
// fp32 W[K][N] -> bf16 WT[N][K].
// ---------------------------------------------------------------------------
__global__ __launch_bounds__(256) void transpose_cvt_kernel(
    const float* __restrict__ in, bf16_t* __restrict__ out, int K, int N)
{
  int nc = threadIdx.x & 63;
  int kg = threadIdx.x >> 6;
  int n  = blockIdx.x * 64 + nc;
  int kb = blockIdx.y * 32 + kg * 8;
  bf16x8 v;
  #pragma unroll
  for (int i = 0; i < 8; ++i) v[i] = (bf16_t)in[(size_t)(kb + i) * N + n];
  *(bf16x8*)(out + (size_t)n * K + kb) = v;
}

// ---------------------------------------------------------------------------
// Extract V^T from qkv: vtg[b][d][s] = qkv[b*S+s][2176+d].
// ---------------------------------------------------------------------------
__global__ __launch_bounds__(256) void vt_extract_kernel(
    const bf16_t* __restrict__ qkv, bf16_t* __restrict__ vtg)
{
  int d  = threadIdx.x & 127;
  int sg = threadIdx.x >> 7;
  int b  = blockIdx.y;
  int s8 = blockIdx.x * 2 + sg;
  bf16x8 v;
  #pragma unroll
  for (int i = 0; i < 8; ++i)
    v[i] = qkv[((size_t)(b * S_LEN + s8 * 8 + i)) * QKVN + HID + HD + d];
  *(bf16x8*)(vtg + ((size_t)(b * HD + d)) * S_LEN + s8 * 8) = v;
}

// ---------------------------------------------------------------------------
// GEMM: C[M,N] = A[M,K] @ WT^T + bias (WT pre-transposed [N][K]).
// m97 structure: 128x128 C-tile, BK=32, 4 waves as 2x2, wave owns 64x64
// patch (acc[4][4]). BOTH A and B tiles staged via global_load_lds width=16
// into unpadded stride-32 LDS. Per wave per K-step: 4 DMA issues,
// 8 ds_read_b128, 16 MFMA.
// ---------------------------------------------------------------------------
template <typename OutT>
__global__ __launch_bounds__(256) void gemm_bias_kernel(
    const bf16_t* __restrict__ A, const bf16_t* __restrict__ WT,
    const float* __restrict__ bias, OutT* __restrict__ C,
    int K, int lda, int ldc)
{
  __shared__ bf16_t Ash[128 * 32];   // [m][k], NO padding (lds-dma)
  __shared__ bf16_t Bsh[128 * 32];   // [n][k], NO padding

  const int tid  = threadIdx.x;
  const int wave = tid >> 6;
  const int lane = tid & 63;
  const int quad = lane >> 4;
  const int c16  = lane & 15;
  const int wm = wave >> 1;          // 0..1 : row half
  const int wn = wave & 1;           // 0..1 : col half
  const int n0 = blockIdx.x * 128;
  const int m0 = blockIdx.y * 128;

  f32x4 acc[4][4] = {};

  for (int k0 = 0; k0 < K; k0 += 32) {
    __syncthreads();
    // 512 16B-chunks per tile; wave stages chunks [wave*128, wave*128+128)
    #pragma unroll
    for (int j = 0; j < 2; ++j) {
      int cbase = wave * 128 + j * 64;       // uniform per wave-issue
      int c = cbase + lane;
      int row = c >> 2, kc = c & 3;
      gld_lds16(A  + (size_t)(m0 + row) * lda + k0 + kc * 8, Ash + cbase * 8);
      gld_lds16(WT + (size_t)(n0 + row) * K   + k0 + kc * 8, Bsh + cbase * 8);
    }
    __syncthreads();

    bf16x8 af[4], bfr[4];
    #pragma unroll
    for (int rb = 0; rb < 4; ++rb)
      af[rb] = *(const bf16x8*)(Ash + (wm * 64 + rb * 16 + c16) * 32 + quad * 8);
    #pragma unroll
    for (int nt = 0; nt < 4; ++nt)
      bfr[nt] = *(const bf16x8*)(Bsh + (wn * 64 + nt * 16 + c16) * 32 + quad * 8);

    #pragma unroll
    for (int rb = 0; rb < 4; ++rb)
      #pragma unroll
      for (int nt = 0; nt < 4; ++nt)
        acc[rb][nt] = __builtin_amdgcn_mfma_f32_16x16x32_bf16(af[rb], bfr[nt],
                                                              acc[rb][nt], 0, 0, 0);
  }

  #pragma unroll
  for (int nt = 0; nt < 4; ++nt) {
    int col = n0 + wn * 64 + nt * 16 + c16;
    float bv = bias[col];
    #pragma unroll
    for (int rb = 0; rb < 4; ++rb) {
      int rbase = m0 + wm * 64 + rb * 16 + quad * 4;
      #pragma unroll
      for (int r = 0; r < 4; ++r)
        C[(size_t)(rbase + r) * ldc + col] = (OutT)(acc[rb][nt][r] + bv);
    }
  }
}

// ---------------------------------------------------------------------------
// Causal MQA attention, S^T formulation, 8 waves / 512 threads.
// (unchanged from round 4 — see commit notes; latency-bound, attacked next)
// ---------------------------------------------------------------------------
__global__ __launch_bounds__(512, 4) void mqa_attn_kernel(
    const bf16_t* __restrict__ qkv, const bf16_t* __restrict__ vtg,
    bf16_t* __restrict__ out)
{
  __shared__ bf16_t Ksh[2][64 * 136];   // per-group K tile / P scratch / O scratch
  __shared__ bf16_t VTsh[2][128 * 72];  // per-group V^T tile / f32 combine scratch

  const int tid  = threadIdx.x;
  const int wave = tid >> 6;
  const int g    = wave >> 2;        // key-parity group
  const int wv   = wave & 3;         // q-strip within tile
  const int lane = tid & 63;
  const int quad = lane >> 4;
  const int c16  = lane & 15;
  const int gt   = tid & 255;        // thread id within group
  const int h = blockIdx.y;
  const int b = blockIdx.z;
  const float qscale = 0.08838834764831845f * 1.4426950408889634f; // /sqrt(128)*log2e

  const bf16_t* kbase = qkv + (size_t)b * S_LEN * QKVN + HID;
  const bf16_t* vtb   = vtg + (size_t)b * HD * S_LEN;

  for (int half = 0; half < 2; ++half) {
    const int qb = half ? (31 - (int)blockIdx.x) : (int)blockIdx.x;
    const int q0 = qb * 64;
    const int qrow = q0 + wv * 16 + c16;

    const bf16_t* qp = qkv + ((size_t)(b * S_LEN + qrow)) * QKVN + h * HD;
    bf16x8 qf[4];
    #pragma unroll
    for (int ks = 0; ks < 4; ++ks) {
      bf16x8 t = *(const bf16x8*)(qp + ks * 32 + quad * 8);
      #pragma unroll
      for (int j = 0; j < 8; ++j) t[j] = (bf16_t)((float)t[j] * qscale);
      qf[ks] = t;
    }

    float m_q = NEG_BIG, l_q = 0.0f;
    f32x4 o[8] = {};
    const int nss = (qb + 2) >> 1;

    for (int ss = 0; ss < nss; ++ss) {
      const int kt = 2 * ss + g;
      const bool active = (kt <= qb);

      __syncthreads();
      if (active) {
        for (int c = gt; c < 1024; c += 256) {
          int key = c >> 4, dc = c & 15;
          *(bf16x8*)(&Ksh[g][key * 136 + dc * 8]) =
              *(const bf16x8*)(kbase + (size_t)(kt * 64 + key) * QKVN + dc * 8);
        }
        for (int c = gt; c < 1024; c += 256) {
          int d = c >> 3, kc = c & 7;
          *(bf16x8*)(&VTsh[g][d * 72 + kc * 8]) =
              *(const bf16x8*)(vtb + (size_t)d * S_LEN + kt * 64 + kc * 8);
        }
      }
      __syncthreads();

      float p[4][4];
      if (active) {
        f32x4 sacc[4] = {};
        #pragma unroll
        for (int mt = 0; mt < 4; ++mt) {
          #pragma unroll
          for (int ks = 0; ks < 4; ++ks) {
            bf16x8 kf = *(const bf16x8*)(&Ksh[g][(mt * 16 + c16) * 136 + ks * 32 + quad * 8]);
            sacc[mt] = __builtin_amdgcn_mfma_f32_16x16x32_bf16(kf, qf[ks], sacc[mt], 0, 0, 0);
          }
        }
        float mx = NEG_BIG;
        if (kt == qb) {
          #pragma unroll
          for (int mt = 0; mt < 4; ++mt) {
            #pragma unroll
            for (int r = 0; r < 4; ++r) {
              int key = kt * 64 + mt * 16 + quad * 4 + r;
              float v = sacc[mt][r];
              if (key > qrow) v = NEG_BIG;
              p[mt][r] = v;
              mx = fmaxf(mx, v);
            }
          }
        } else {
          #pragma unroll
          for (int mt = 0; mt < 4; ++mt) {
            #pragma unroll
            for (int r = 0; r < 4; ++r) {
              p[mt][r] = sacc[mt][r];
              mx = fmaxf(mx, sacc[mt][r]);
            }
          }
        }
        mx = fmaxf(mx, __shfl_xor(mx, 16));
        mx = fmaxf(mx, __shfl_xor(mx, 32));

        float mn = fmaxf(m_q, mx);
        float alpha = __builtin_exp2f(m_q - mn);
        m_q = mn;

        float rs = 0.f;
        #pragma unroll
        for (int mt = 0; mt < 4; ++mt) {
          #pragma unroll
          for (int r = 0; r < 4; ++r) {
            float pe = __builtin_exp2f(p[mt][r] - m_q);
            p[mt][r] = pe;
            rs += pe;
          }
        }
        rs += __shfl_xor(rs, 16);
        rs += __shfl_xor(rs, 32);
        l_q = l_q * alpha + rs;
        #pragma unroll
        for (int mt8 = 0; mt8 < 8; ++mt8) {
          #pragma unroll
          for (int r = 0; r < 4; ++r) o[mt8][r] *= alpha;
        }
      }

      __syncthreads();   // all K-tile reads done -> Ksh[g] reusable for P
      if (active) {
        bf16_t* Pw = &Ksh[g][(wv * 16) * 136];
        #pragma unroll
        for (int mt = 0; mt < 4; ++mt) {
          bf16x4 pk;
          #pragma unroll
          for (int r = 0; r < 4; ++r) pk[r] = (bf16_t)p[mt][r];
          *(bf16x4*)(Pw + c16 * 136 + mt * 16 + quad * 4) = pk;
        }
        bf16x8 pf[2];
        #pragma unroll
        for (int kh = 0; kh < 2; ++kh)
          pf[kh] = *(const bf16x8*)(Pw + c16 * 136 + kh * 32 + quad * 8);
        #pragma unroll
        for (int mt8 = 0; mt8 < 8; ++mt8) {
          #pragma unroll
          for (int kh = 0; kh < 2; ++kh) {
            bf16x8 vf = *(const bf16x8*)(&VTsh[g][(mt8 * 16 + c16) * 72 + kh * 32 + quad * 8]);
            o[mt8] = __builtin_amdgcn_mfma_f32_16x16x32_bf16(vf, pf[kh], o[mt8], 0, 0, 0);
          }
        }
      }
    }

    // ---- merge parity groups ----
    __syncthreads();
    float* scr = (float*)&VTsh[0][0];
    float* mls = scr + 4 * 16 * 132;
    if (g == 1) {
      float* op = scr + (wv * 16 + c16) * 132;
      #pragma unroll
      for (int mt8 = 0; mt8 < 8; ++mt8)
        *(f32x4*)(op + mt8 * 16 + quad * 4) = o[mt8];
      if (quad == 0) {
        mls[wv * 32 + c16] = m_q;
        mls[wv * 32 + 16 + c16] = l_q;
      }
    }
    __syncthreads();
    if (g == 0) {
      float m1 = mls[wv * 32 + c16];
      float l1 = mls[wv * 32 + 16 + c16];
      float mF = fmaxf(m_q, m1);
      float a0 = __builtin_exp2f(m_q - mF);
      float a1 = __builtin_exp2f(m1 - mF);
      float inv = 1.0f / fmaxf(a0 * l_q + a1 * l1, 1e-20f);
      a0 *= inv; a1 *= inv;
      const float* op = scr + (wv * 16 + c16) * 132;
      bf16_t* Osh = &Ksh[0][(wv * 16) * 136];
      #pragma unroll
      for (int mt8 = 0; mt8 < 8; ++mt8) {
        f32x4 o1 = *(const f32x4*)(op + mt8 * 16 + quad * 4);
        bf16x4 pk;
        #pragma unroll
        for (int r = 0; r < 4; ++r) pk[r] = (bf16_t)(o[mt8][r] * a0 + o1[r] * a1);
        *(bf16x4*)(Osh + c16 * 136 + mt8 * 16 + quad * 4) = pk;
      }
      int ql = lane >> 2, dc = lane & 3;
      #pragma unroll
      for (int i = 0; i < 4; ++i) {
        bf16x8 v = *(const bf16x8*)(Osh + ql * 136 + dc * 8 + i * 32);
        *(bf16x8*)(out + ((size_t)(b * S_LEN + q0 + wv * 16 + ql)) * HID
                       + h * HD + dc * 8 + i * 32) = v;
      }
    }
  }
}

extern "C" void kernel_launch(void* const* d_in, const int* in_sizes, int n_in,
                              void* d_out, int out_size, void* d_ws, size_t ws_size,
                              hipStream_t stream) {
  const float* hidden_f   = (const float*)d_in[0];
  // d_in[1] = attention_mask (deterministic causal) -- ignored
  const float* c_attn_w_f = (const float*)d_in[2];
  const float* c_attn_b_f = (const float*)d_in[3];
  const float* c_proj_w_f = (const float*)d_in[4];
  const float* c_proj_b_f = (const float*)d_in[5];
  float* out = (float*)d_out;

  const int M = 2 * S_LEN;                 // 4096
  const int nH  = M * HID;
  const int nWq = HID * QKVN;
  const int nWp = HID * HID;

  bf16_t* hbf   = (bf16_t*)d_ws;
  bf16_t* wqT   = hbf  + nH;               // WT_qkv [2304][2048]
  bf16_t* wpT   = wqT  + nWq;              // WT_proj[2048][2048]
  bf16_t* qkv   = wpT  + nWp;              // [4096][2304]
  bf16_t* attn  = qkv  + (size_t)M * QKVN; // [4096][2048]
  bf16_t* vtg   = attn + (size_t)M * HID;  // V^T [2][128][2048]

  cvt_f32_bf16_kernel<<<nH / 1024, 256, 0, stream>>>(hidden_f, hbf, nH);
  dim3 gt1(QKVN / 64, HID / 32);
  transpose_cvt_kernel<<<gt1, 256, 0, stream>>>(c_attn_w_f, wqT, HID, QKVN);
  dim3 gt2(HID / 64, HID / 32);
  transpose_cvt_kernel<<<gt2, 256, 0, stream>>>(c_proj_w_f, wpT, HID, HID);

  dim3 g1(QKVN / 128, M / 128);
  gemm_bias_kernel<bf16_t><<<g1, 256, 0, stream>>>(hbf, wqT, c_attn_b_f, qkv,
                                                   HID, HID, QKVN);

  dim3 gv(S_LEN / 16, 2);
  vt_extract_kernel<<<gv, 256, 0, stream>>>(qkv, vtg);

  dim3 g2(16, NH, 2);
  mqa_attn_kernel<<<g2, 512, 0, stream>>>(qkv, vtg, attn);

  dim3 g3(HID / 128, M / 128);
  gemm_bias_kernel<float><<<g3, 256, 0, stream>>>(attn, wpT, c_proj_b_f, out,
                                                  HID, HID, HID);
}

// Round 6
// 341.514 us; speedup vs baseline: 2.6570x; 1.0058x over previous
//
#include <hip/hip_runtime.h>
#include <hip/hip_bf16.h>

typedef __bf16 bf16_t;
typedef __bf16 bf16x8 __attribute__((ext_vector_type(8)));
typedef __bf16 bf16x4 __attribute__((ext_vector_type(4)));
typedef float f32x4 __attribute__((ext_vector_type(4)));

#define S_LEN 2048
#define HID   2048
#define NH    16
#define HD    128
#define QKVN  2304   // 2048 + 2*128
#define NEG_BIG (-30000.0f)

// direct global->LDS DMA, 16B per lane. lds dst must be the WAVE-UNIFORM base;
// HW adds lane*16 itself (m104). No LDS padding allowed in the covered range.
__device__ __forceinline__ void gld_lds16(const bf16_t* g, bf16_t* l) {
  __builtin_amdgcn_global_load_lds(
      (const __attribute__((address_space(1))) void*)((const void*)g),
      (__attribute__((address_space(3))) void*)((void*)l), 16, 0, 0);
}

// ---------------------------------------------------------------------------
// fp32 -> bf16 downcast, float4-vectorized.
// ---------------------------------------------------------------------------
__global__ __launch_bounds__(256) void cvt_f32_bf16_kernel(
    const float* __restrict__ in, bf16_t* __restrict__ out, int n)
{
  int i = (blockIdx.x * 256 + threadIdx.x) * 4;
  if (i < n) {
    float4 v = *(const float4*)(in + i);
    bf16x4 o;
    o[0] = (bf16_t)v.x; o[1] = (bf16_t)v.y; o[2] = (bf16_t)v.z; o[3] = (bf16_t)v.w;
    *(bf16x4*)(out + i) = o;
  }
}

// ---------------------------------------------------------------------------
// fp32 W[K][N] -> bf16 WT[N][K].
// ---------------------------------------------------------------------------
__global__ __launch_bounds__(256) void transpose_cvt_kernel(
    const float* __restrict__ in, bf16_t* __restrict__ out, int K, int N)
{
  int nc = threadIdx.x & 63;
  int kg = threadIdx.x >> 6;
  int n  = blockIdx.x * 64 + nc;
  int kb = blockIdx.y * 32 + kg * 8;
  bf16x8 v;
  #pragma unroll
  for (int i = 0; i < 8; ++i) v[i] = (bf16_t)in[(size_t)(kb + i) * N + n];
  *(bf16x8*)(out + (size_t)n * K + kb) = v;
}

// ---------------------------------------------------------------------------
// Extract V^T from qkv: vtg[b][d][s] = qkv[b*S+s][2176+d].
// ---------------------------------------------------------------------------
__global__ __launch_bounds__(256) void vt_extract_kernel(
    const bf16_t* __restrict__ qkv, bf16_t* __restrict__ vtg)
{
  int d  = threadIdx.x & 127;
  int sg = threadIdx.x >> 7;
  int b  = blockIdx.y;
  int s8 = blockIdx.x * 2 + sg;
  bf16x8 v;
  #pragma unroll
  for (int i = 0; i < 8; ++i)
    v[i] = qkv[((size_t)(b * S_LEN + s8 * 8 + i)) * QKVN + HID + HD + d];
  *(bf16x8*)(vtg + ((size_t)(b * HD + d)) * S_LEN + s8 * 8) = v;
}

// ---------------------------------------------------------------------------
// GEMM: C[M,N] = A[M,K] @ WT^T + bias (WT pre-transposed [N][K]).
// 128x128 C-tile, BK=64, 4 waves as 2x2 (wave owns 64x64, acc[4][4]).
// Both tiles staged via global_load_lds width=16 into unpadded stride-64
// LDS with XOR chunk swizzle (kc_phys = kc_log ^ (row&7)):
//  - DMA side: slot c receives global chunk (row=c>>3, kc=(c^row)&7) -> each
//    8-lane row-group still covers one contiguous 128B segment (coalesced).
//  - read side: fragment (row, kk*4+quad) is at kc_phys=((kk*4+quad)^row)&7
//    -> banks spread over all 8 4-bank windows, 2 lanes each (free).
// Per wave per K-step: 8 DMA issues, 16 ds_read_b128, 32 MFMA; 32 barriers
// total (vs 64 at BK=32) -> 2x compute per barrier-drain.
// ---------------------------------------------------------------------------
template <typename OutT>
__global__ __launch_bounds__(256) void gemm_bias_kernel(
    const bf16_t* __restrict__ A, const bf16_t* __restrict__ WT,
    const float* __restrict__ bias, OutT* __restrict__ C,
    int K, int lda, int ldc)
{
  __shared__ bf16_t Ash[128 * 64];   // [m][k] swizzled, NO padding (lds-dma)
  __shared__ bf16_t Bsh[128 * 64];   // [n][k] swizzled, NO padding

  const int tid  = threadIdx.x;
  const int wave = tid >> 6;
  const int lane = tid & 63;
  const int quad = lane >> 4;
  const int c16  = lane & 15;
  const int wm = wave >> 1;          // 0..1 : row half
  const int wn = wave & 1;           // 0..1 : col half
  const int n0 = blockIdx.x * 128;
  const int m0 = blockIdx.y * 128;

  f32x4 acc[4][4] = {};

  for (int k0 = 0; k0 < K; k0 += 64) {
    __syncthreads();
    // 1024 16B-chunks per operand tile; wave stages [wave*256, wave*256+256)
    #pragma unroll
    for (int j = 0; j < 4; ++j) {
      int cbase = wave * 256 + j * 64;        // wave-uniform LDS base
      int c = cbase + lane;
      int row = c >> 3;
      int kcl = (c ^ row) & 7;                // xor-permuted chunk fetch
      gld_lds16(A  + (size_t)(m0 + row) * lda + k0 + kcl * 8, Ash + cbase * 8);
      gld_lds16(WT + (size_t)(n0 + row) * K   + k0 + kcl * 8, Bsh + cbase * 8);
    }
    __syncthreads();

    #pragma unroll
    for (int kk = 0; kk < 2; ++kk) {
      bf16x8 af[4], bfr[4];
      #pragma unroll
      for (int rb = 0; rb < 4; ++rb) {
        int row = wm * 64 + rb * 16 + c16;
        int kcp = ((kk * 4 + quad) ^ row) & 7;
        af[rb] = *(const bf16x8*)(Ash + row * 64 + kcp * 8);
      }
      #pragma unroll
      for (int nt = 0; nt < 4; ++nt) {
        int row = wn * 64 + nt * 16 + c16;
        int kcp = ((kk * 4 + quad) ^ row) & 7;
        bfr[nt] = *(const bf16x8*)(Bsh + row * 64 + kcp * 8);
      }
      #pragma unroll
      for (int rb = 0; rb < 4; ++rb)
        #pragma unroll
        for (int nt = 0; nt < 4; ++nt)
          acc[rb][nt] = __builtin_amdgcn_mfma_f32_16x16x32_bf16(af[rb], bfr[nt],
                                                                acc[rb][nt], 0, 0, 0);
    }
  }

  #pragma unroll
  for (int nt = 0; nt < 4; ++nt) {
    int col = n0 + wn * 64 + nt * 16 + c16;
    float bv = bias[col];
    #pragma unroll
    for (int rb = 0; rb < 4; ++rb) {
      int rbase = m0 + wm * 64 + rb * 16 + quad * 4;
      #pragma unroll
      for (int r = 0; r < 4; ++r)
        C[(size_t)(rbase + r) * ldc + col] = (OutT)(acc[rb][nt][r] + bv);
    }
  }
}

// ---------------------------------------------------------------------------
// Causal MQA attention, S^T formulation, 8 waves / 512 threads.
// (unchanged — latency-bound at ~52% combined pipe busy; conflicts are
// near-minimum b128 phasing per m98 evidence, not the limiter)
// ---------------------------------------------------------------------------
__global__ __launch_bounds__(512, 4) void mqa_attn_kernel(
    const bf16_t* __restrict__ qkv, const bf16_t* __restrict__ vtg,
    bf16_t* __restrict__ out)
{
  __shared__ bf16_t Ksh[2][64 * 136];   // per-group K tile / P scratch / O scratch
  __shared__ bf16_t VTsh[2][128 * 72];  // per-group V^T tile / f32 combine scratch

  const int tid  = threadIdx.x;
  const int wave = tid >> 6;
  const int g    = wave >> 2;        // key-parity group
  const int wv   = wave & 3;         // q-strip within tile
  const int lane = tid & 63;
  const int quad = lane >> 4;
  const int c16  = lane & 15;
  const int gt   = tid & 255;        // thread id within group
  const int h = blockIdx.y;
  const int b = blockIdx.z;
  const float qscale = 0.08838834764831845f * 1.4426950408889634f; // /sqrt(128)*log2e

  const bf16_t* kbase = qkv + (size_t)b * S_LEN * QKVN + HID;
  const bf16_t* vtb   = vtg + (size_t)b * HD * S_LEN;

  for (int half = 0; half < 2; ++half) {
    const int qb = half ? (31 - (int)blockIdx.x) : (int)blockIdx.x;
    const int q0 = qb * 64;
    const int qrow = q0 + wv * 16 + c16;

    const bf16_t* qp = qkv + ((size_t)(b * S_LEN + qrow)) * QKVN + h * HD;
    bf16x8 qf[4];
    #pragma unroll
    for (int ks = 0; ks < 4; ++ks) {
      bf16x8 t = *(const bf16x8*)(qp + ks * 32 + quad * 8);
      #pragma unroll
      for (int j = 0; j < 8; ++j) t[j] = (bf16_t)((float)t[j] * qscale);
      qf[ks] = t;
    }

    float m_q = NEG_BIG, l_q = 0.0f;
    f32x4 o[8] = {};
    const int nss = (qb + 2) >> 1;

    for (int ss = 0; ss < nss; ++ss) {
      const int kt = 2 * ss + g;
      const bool active = (kt <= qb);

      __syncthreads();
      if (active) {
        for (int c = gt; c < 1024; c += 256) {
          int key = c >> 4, dc = c & 15;
          *(bf16x8*)(&Ksh[g][key * 136 + dc * 8]) =
              *(const bf16x8*)(kbase + (size_t)(kt * 64 + key) * QKVN + dc * 8);
        }
        for (int c = gt; c < 1024; c += 256) {
          int d = c >> 3, kc = c & 7;
          *(bf16x8*)(&VTsh[g][d * 72 + kc * 8]) =
              *(const bf16x8*)(vtb + (size_t)d * S_LEN + kt * 64 + kc * 8);
        }
      }
      __syncthreads();

      float p[4][4];
      if (active) {
        f32x4 sacc[4] = {};
        #pragma unroll
        for (int mt = 0; mt < 4; ++mt) {
          #pragma unroll
          for (int ks = 0; ks < 4; ++ks) {
            bf16x8 kf = *(const bf16x8*)(&Ksh[g][(mt * 16 + c16) * 136 + ks * 32 + quad * 8]);
            sacc[mt] = __builtin_amdgcn_mfma_f32_16x16x32_bf16(kf, qf[ks], sacc[mt], 0, 0, 0);
          }
        }
        float mx = NEG_BIG;
        if (kt == qb) {
          #pragma unroll
          for (int mt = 0; mt < 4; ++mt) {
            #pragma unroll
            for (int r = 0; r < 4; ++r) {
              int key = kt * 64 + mt * 16 + quad * 4 + r;
              float v = sacc[mt][r];
              if (key > qrow) v = NEG_BIG;
              p[mt][r] = v;
              mx = fmaxf(mx, v);
            }
          }
        } else {
          #pragma unroll
          for (int mt = 0; mt < 4; ++mt) {
            #pragma unroll
            for (int r = 0; r < 4; ++r) {
              p[mt][r] = sacc[mt][r];
              mx = fmaxf(mx, sacc[mt][r]);
            }
          }
        }
        mx = fmaxf(mx, __shfl_xor(mx, 16));
        mx = fmaxf(mx, __shfl_xor(mx, 32));

        float mn = fmaxf(m_q, mx);
        float alpha = __builtin_exp2f(m_q - mn);
        m_q = mn;

        float rs = 0.f;
        #pragma unroll
        for (int mt = 0; mt < 4; ++mt) {
          #pragma unroll
          for (int r = 0; r < 4; ++r) {
            float pe = __builtin_exp2f(p[mt][r] - m_q);
            p[mt][r] = pe;
            rs += pe;
          }
        }
        rs += __shfl_xor(rs, 16);
        rs += __shfl_xor(rs, 32);
        l_q = l_q * alpha + rs;
        #pragma unroll
        for (int mt8 = 0; mt8 < 8; ++mt8) {
          #pragma unroll
          for (int r = 0; r < 4; ++r) o[mt8][r] *= alpha;
        }
      }

      __syncthreads();   // all K-tile reads done -> Ksh[g] reusable for P
      if (active) {
        bf16_t* Pw = &Ksh[g][(wv * 16) * 136];
        #pragma unroll
        for (int mt = 0; mt < 4; ++mt) {
          bf16x4 pk;
          #pragma unroll
          for (int r = 0; r < 4; ++r) pk[r] = (bf16_t)p[mt][r];
          *(bf16x4*)(Pw + c16 * 136 + mt * 16 + quad * 4) = pk;
        }
        bf16x8 pf[2];
        #pragma unroll
        for (int kh = 0; kh < 2; ++kh)
          pf[kh] = *(const bf16x8*)(Pw + c16 * 136 + kh * 32 + quad * 8);
        #pragma unroll
        for (int mt8 = 0; mt8 < 8; ++mt8) {
          #pragma unroll
          for (int kh = 0; kh < 2; ++kh) {
            bf16x8 vf = *(const bf16x8*)(&VTsh[g][(mt8 * 16 + c16) * 72 + kh * 32 + quad * 8]);
            o[mt8] = __builtin_amdgcn_mfma_f32_16x16x32_bf16(vf, pf[kh], o[mt8], 0, 0, 0);
          }
        }
      }
    }

    // ---- merge parity groups ----
    __syncthreads();
    float* scr = (float*)&VTsh[0][0];
    float* mls = scr + 4 * 16 * 132;
    if (g == 1) {
      float* op = scr + (wv * 16 + c16) * 132;
      #pragma unroll
      for (int mt8 = 0; mt8 < 8; ++mt8)
        *(f32x4*)(op + mt8 * 16 + quad * 4) = o[mt8];
      if (quad == 0) {
        mls[wv * 32 + c16] = m_q;
        mls[wv * 32 + 16 + c16] = l_q;
      }
    }
    __syncthreads();
    if (g == 0) {
      float m1 = mls[wv * 32 + c16];
      float l1 = mls[wv * 32 + 16 + c16];
      float mF = fmaxf(m_q, m1);
      float a0 = __builtin_exp2f(m_q - mF);
      float a1 = __builtin_exp2f(m1 - mF);
      float inv = 1.0f / fmaxf(a0 * l_q + a1 * l1, 1e-20f);
      a0 *= inv; a1 *= inv;
      const float* op = scr + (wv * 16 + c16) * 132;
      bf16_t* Osh = &Ksh[0][(wv * 16) * 136];
      #pragma unroll
      for (int mt8 = 0; mt8 < 8; ++mt8) {
        f32x4 o1 = *(const f32x4*)(op + mt8 * 16 + quad * 4);
        bf16x4 pk;
        #pragma unroll
        for (int r = 0; r < 4; ++r) pk[r] = (bf16_t)(o[mt8][r] * a0 + o1[r] * a1);
        *(bf16x4*)(Osh + c16 * 136 + mt8 * 16 + quad * 4) = pk;
      }
      int ql = lane >> 2, dc = lane & 3;
      #pragma unroll
      for (int i = 0; i < 4; ++i) {
        bf16x8 v = *(const bf16x8*)(Osh + ql * 136 + dc * 8 + i * 32);
        *(bf16x8*)(out + ((size_t)(b * S_LEN + q0 + wv * 16 + ql)) * HID
                       + h * HD + dc * 8 + i * 32) = v;
      }
    }
  }
}

extern "C" void kernel_launch(void* const* d_in, const int* in_sizes, int n_in,
                              void* d_out, int out_size, void* d_ws, size_t ws_size,
                              hipStream_t stream) {
  const float* hidden_f   = (const float*)d_in[0];
  // d_in[1] = attention_mask (deterministic causal) -- ignored
  const float* c_attn_w_f = (const float*)d_in[2];
  const float* c_attn_b_f = (const float*)d_in[3];
  const float* c_proj_w_f = (const float*)d_in[4];
  const float* c_proj_b_f = (const float*)d_in[5];
  float* out = (float*)d_out;

  const int M = 2 * S_LEN;                 // 4096
  const int nH  = M * HID;
  const int nWq = HID * QKVN;
  const int nWp = HID * HID;

  bf16_t* hbf   = (bf16_t*)d_ws;
  bf16_t* wqT   = hbf  + nH;               // WT_qkv [2304][2048]
  bf16_t* wpT   = wqT  + nWq;              // WT_proj[2048][2048]
  bf16_t* qkv   = wpT  + nWp;              // [4096][2304]
  bf16_t* attn  = qkv  + (size_t)M * QKVN; // [4096][2048]
  bf16_t* vtg   = attn + (size_t)M * HID;  // V^T [2][128][2048]

  cvt_f32_bf16_kernel<<<nH / 1024, 256, 0, stream>>>(hidden_f, hbf, nH);
  dim3 gt1(QKVN / 64, HID / 32);
  transpose_cvt_kernel<<<gt1, 256, 0, stream>>>(c_attn_w_f, wqT, HID, QKVN);
  dim3 gt2(HID / 64, HID / 32);
  transpose_cvt_kernel<<<gt2, 256, 0, stream>>>(c_proj_w_f, wpT, HID, HID);

  dim3 g1(QKVN / 128, M / 128);
  gemm_bias_kernel<bf16_t><<<g1, 256, 0, stream>>>(hbf, wqT, c_attn_b_f, qkv,
                                                   HID, HID, QKVN);

  dim3 gv(S_LEN / 16, 2);
  vt_extract_kernel<<<gv, 256, 0, stream>>>(qkv, vtg);

  dim3 g2(16, NH, 2);
  mqa_attn_kernel<<<g2, 512, 0, stream>>>(qkv, vtg, attn);

  dim3 g3(HID / 128, M / 128);
  gemm_bias_kernel<float><<<g3, 256, 0, stream>>>(attn, wpT, c_proj_b_f, out,
                                                  HID, HID, HID);
}